// Round 9
// baseline (157.201 us; speedup 1.0000x reference)
//
#include <hip/hip_runtime.h>

#define NROWS 8192
#define NSPLIT 16
#define JT (NROWS / NSPLIT)  // 512 j's per split
#define NITER (JT / 64)      // 8
#define L2E 1.4426950408889634f

typedef __attribute__((ext_vector_type(4))) float f32x4;
typedef __attribute__((ext_vector_type(8))) __bf16 bf16x8;
typedef __attribute__((ext_vector_type(4))) unsigned int u32x4;

__device__ __forceinline__ unsigned short f2bf(float x) {
  unsigned u = __float_as_uint(x);
  u += 0x7fffu + ((u >> 16) & 1u);
  return (unsigned short)(u >> 16);
}

// ---------------------------------------------------------------------------
// Kernel A: Wh = h@W (stored bf16 in MFMA-B-fragment order), src=Wh@a1, dst=Wh@a2
// src/dst pre-scaled by log2(e) so downstream works in exp2 domain.
// Fragment layout: slot (jc, nt, lane, e) holds Wh[j = 32*jc + 8*(lane>>4) + e][nt*16 + (lane&15)]
// ---------------------------------------------------------------------------
__global__ __launch_bounds__(256) void k_prep(
    const float* __restrict__ h, const float* __restrict__ W,
    const float* __restrict__ a, unsigned short* __restrict__ WhB,
    float* __restrict__ src, float* __restrict__ dst) {
  int i = blockIdx.x * 4 + (threadIdx.x >> 6);  // row
  int lane = threadIdx.x & 63;                  // feature
  const float* hrow = h + (size_t)i * 256;
  float s = 0.f;
#pragma unroll 4
  for (int k = 0; k < 256; k += 4) {
    float4 hv = *(const float4*)(hrow + k);
    s = fmaf(hv.x, W[(k + 0) * 64 + lane], s);
    s = fmaf(hv.y, W[(k + 1) * 64 + lane], s);
    s = fmaf(hv.z, W[(k + 2) * 64 + lane], s);
    s = fmaf(hv.w, W[(k + 3) * 64 + lane], s);
  }
  int nt = lane >> 4, c = lane & 15;
  int gi = (i >> 3) & 3, e = i & 7;
  int idx = ((((i >> 5) * 4 + nt) * 64) + c + 16 * gi) * 8 + e;
  WhB[idx] = f2bf(s);
  float v1 = s * a[lane];
  float v2 = s * a[64 + lane];
#pragma unroll
  for (int d = 32; d; d >>= 1) {
    v1 += __shfl_xor(v1, d);
    v2 += __shfl_xor(v2, d);
  }
  if (lane == 0) {
    src[i] = v1 * L2E;
    dst[i] = v2 * L2E;
  }
}

// ---------------------------------------------------------------------------
// Kernel A2: dmax = max_j dst[j]  (global scalar; 1 block)
// ---------------------------------------------------------------------------
__global__ __launch_bounds__(256) void k_dmax(
    const float* __restrict__ dst, float* __restrict__ dmax) {
  __shared__ float red[4];
  float v = -INFINITY;
  for (int i = threadIdx.x; i < NROWS; i += 256) v = fmaxf(v, dst[i]);
#pragma unroll
  for (int d = 32; d; d >>= 1) v = fmaxf(v, __shfl_xor(v, d));
  if ((threadIdx.x & 63) == 0) red[threadIdx.x >> 6] = v;
  __syncthreads();
  if (threadIdx.x == 0)
    *dmax = fmaxf(fmaxf(red[0], red[1]), fmaxf(red[2], red[3]));
}

// ---------------------------------------------------------------------------
// Kernel B (FUSED, ILP x2): in-wave ballot-pack + masked-softmax + PV for
// TWO 16-row tiles per wave (32 consecutive rows), halved j-range
// (NSPLIT=16). Two independent dependency chains per wave fill each
// other's stall slots; B-fragments are loaded once and feed both tiles.
//
// Phase 1: pack 32 rows x 512 cols via coalesced loads + ballot ->
// mask(rr, ch) in reg mk[ch>>1] of lane 32*(ch&1)+rr (4 u64/lane).
// Phase 2: per 64-col iter, two shfl fetches (tile A row r, tile B row
// 16+r); bits gate exp2(lrelu(src+dst) - Mi), bound Mi = lrelu(src_i+dmax);
// 16 MFMA/iter (8 per tile, shared B).
// ---------------------------------------------------------------------------
__global__ __launch_bounds__(256, 4) void k_attn(
    const int* __restrict__ adj, const unsigned short* __restrict__ WhB,
    const float* __restrict__ src, const float* __restrict__ dst,
    const float* __restrict__ dmax,
    float* __restrict__ pl, float* __restrict__ pacc) {
  __shared__ float ldst[JT];
  int task = blockIdx.x * 4 + (threadIdx.x >> 6);  // 0 .. 4095
  int sp = task >> 8;                              // split 0..15 (block-uniform)
  int pt = task & 255;                             // tile-pair index
  int lane = threadIdx.x & 63;
  int r = lane & 15;  // row within tile / C col
  int g = lane >> 4;  // k-slot group
  int row0p = pt * 32;                             // first row of the pair
  int jbase = sp * JT;

  // stage this split's dst slice to LDS (block-shared)
  for (int k = threadIdx.x; k < JT; k += 256) ldst[k] = dst[jbase + k];
  __syncthreads();

  // ---- Phase 1: ballot-pack 32 rows x 512 cols into 4 u64 regs/lane ----
  unsigned long long mk0 = 0, mk1 = 0, mk2 = 0, mk3 = 0;
  {
    const int* abase = adj + (size_t)row0p * NROWS + jbase + lane;
#pragma unroll
    for (int rr = 0; rr < 32; ++rr) {
      const int* rp = abase + (size_t)rr * NROWS;
#pragma unroll
      for (int ch = 0; ch < 8; ++ch) {
        int v = rp[ch * 64];
        unsigned long long bal = __ballot(v > 0);
        const int holder = ((ch & 1) << 5) + rr;
        if ((ch >> 1) == 0) mk0 = (lane == holder) ? bal : mk0;
        if ((ch >> 1) == 1) mk1 = (lane == holder) ? bal : mk1;
        if ((ch >> 1) == 2) mk2 = (lane == holder) ? bal : mk2;
        if ((ch >> 1) == 3) mk3 = (lane == holder) ? bal : mk3;
      }
    }
  }

  float dmv = *dmax;
  float srcA = src[row0p + r];
  float srcB = src[row0p + 16 + r];
  float vA = srcA + dmv, vBv = srcB + dmv;
  float MiA = fmaxf(vA, 0.2f * vA);   // upper bound, tile A rows
  float MiB = fmaxf(vBv, 0.2f * vBv); // upper bound, tile B rows

  float lrA = 0.f, lrB = 0.f;
  f32x4 accA[4] = {f32x4{0.f, 0.f, 0.f, 0.f}, f32x4{0.f, 0.f, 0.f, 0.f},
                   f32x4{0.f, 0.f, 0.f, 0.f}, f32x4{0.f, 0.f, 0.f, 0.f}};
  f32x4 accB[4] = {f32x4{0.f, 0.f, 0.f, 0.f}, f32x4{0.f, 0.f, 0.f, 0.f},
                   f32x4{0.f, 0.f, 0.f, 0.f}, f32x4{0.f, 0.f, 0.f, 0.f}};
  const bf16x8* Bfr = (const bf16x8*)WhB;

#define PE(P, BIT, DD, SRC, MI)           \
  {                                       \
    float v_ = (SRC) + (DD);              \
    v_ = fmaxf(v_, 0.2f * v_);            \
    float e_ = exp2f(v_ - (MI));          \
    (P) = (BIT) ? e_ : 0.f;               \
  }

#pragma unroll 1
  for (int it = 0; it < NITER; ++it) {
    // masks for chunk it: tile A row r, tile B row 16+r
    int sel = it >> 1;
    unsigned long long msrc = (sel == 0) ? mk0
                            : (sel == 1) ? mk1
                            : (sel == 2) ? mk2 : mk3;
    int lsub = (it & 1) << 5;
    unsigned long long pwA = __shfl(msrc, lsub + r);
    unsigned long long pwB = __shfl(msrc, lsub + 16 + r);

    // B fragments for cols [jbase+64*it, +64): shared by both tiles
    int jc = sp * 16 + 2 * it;
    const bf16x8* bp = Bfr + (size_t)jc * 256 + lane;
    bf16x8 b0 = bp[0];
    bf16x8 b1 = bp[64];
    bf16x8 b2 = bp[128];
    bf16x8 b3 = bp[192];
    bf16x8 b4 = bp[256];
    bf16x8 b5 = bp[320];
    bf16x8 b6 = bp[384];
    bf16x8 b7 = bp[448];

    // dst from LDS (4 addresses per wave -> broadcast, conflict-free)
    const float* dl = ldst + it * 64 + 8 * g;
    float4 d0 = *(const float4*)(dl);
    float4 d1 = *(const float4*)(dl + 4);
    float4 d2 = *(const float4*)(dl + 32);
    float4 d3 = *(const float4*)(dl + 36);

    unsigned loA = (unsigned)(pwA >> (8 * g)), hiA = (unsigned)(pwA >> (32 + 8 * g));
    unsigned loB = (unsigned)(pwB >> (8 * g)), hiB = (unsigned)(pwB >> (32 + 8 * g));

    // ---- tile A fragments ----
    float p0, p1, p2, p3, p4, p5, p6, p7;
    PE(p0, loA & 1u, d0.x, srcA, MiA)   PE(p1, loA & 2u, d0.y, srcA, MiA)
    PE(p2, loA & 4u, d0.z, srcA, MiA)   PE(p3, loA & 8u, d0.w, srcA, MiA)
    PE(p4, loA & 16u, d1.x, srcA, MiA)  PE(p5, loA & 32u, d1.y, srcA, MiA)
    PE(p6, loA & 64u, d1.z, srcA, MiA)  PE(p7, loA & 128u, d1.w, srcA, MiA)
    lrA += ((p0 + p1) + (p2 + p3)) + ((p4 + p5) + (p6 + p7));
    unsigned qa0, qa1, qa2, qa3;
    asm("v_cvt_pk_bf16_f32 %0, %1, %2" : "=v"(qa0) : "v"(p0), "v"(p1));
    asm("v_cvt_pk_bf16_f32 %0, %1, %2" : "=v"(qa1) : "v"(p2), "v"(p3));
    asm("v_cvt_pk_bf16_f32 %0, %1, %2" : "=v"(qa2) : "v"(p4), "v"(p5));
    asm("v_cvt_pk_bf16_f32 %0, %1, %2" : "=v"(qa3) : "v"(p6), "v"(p7));
    PE(p0, hiA & 1u, d2.x, srcA, MiA)   PE(p1, hiA & 2u, d2.y, srcA, MiA)
    PE(p2, hiA & 4u, d2.z, srcA, MiA)   PE(p3, hiA & 8u, d2.w, srcA, MiA)
    PE(p4, hiA & 16u, d3.x, srcA, MiA)  PE(p5, hiA & 32u, d3.y, srcA, MiA)
    PE(p6, hiA & 64u, d3.z, srcA, MiA)  PE(p7, hiA & 128u, d3.w, srcA, MiA)
    lrA += ((p0 + p1) + (p2 + p3)) + ((p4 + p5) + (p6 + p7));
    unsigned qa4, qa5, qa6, qa7;
    asm("v_cvt_pk_bf16_f32 %0, %1, %2" : "=v"(qa4) : "v"(p0), "v"(p1));
    asm("v_cvt_pk_bf16_f32 %0, %1, %2" : "=v"(qa5) : "v"(p2), "v"(p3));
    asm("v_cvt_pk_bf16_f32 %0, %1, %2" : "=v"(qa6) : "v"(p4), "v"(p5));
    asm("v_cvt_pk_bf16_f32 %0, %1, %2" : "=v"(qa7) : "v"(p6), "v"(p7));
    u32x4 qvA0 = {qa0, qa1, qa2, qa3};
    u32x4 qvA1 = {qa4, qa5, qa6, qa7};
    bf16x8 A0 = __builtin_bit_cast(bf16x8, qvA0);
    bf16x8 A1 = __builtin_bit_cast(bf16x8, qvA1);

    // ---- tile B fragments (independent chain) ----
    PE(p0, loB & 1u, d0.x, srcB, MiB)   PE(p1, loB & 2u, d0.y, srcB, MiB)
    PE(p2, loB & 4u, d0.z, srcB, MiB)   PE(p3, loB & 8u, d0.w, srcB, MiB)
    PE(p4, loB & 16u, d1.x, srcB, MiB)  PE(p5, loB & 32u, d1.y, srcB, MiB)
    PE(p6, loB & 64u, d1.z, srcB, MiB)  PE(p7, loB & 128u, d1.w, srcB, MiB)
    lrB += ((p0 + p1) + (p2 + p3)) + ((p4 + p5) + (p6 + p7));
    unsigned qb0, qb1, qb2, qb3;
    asm("v_cvt_pk_bf16_f32 %0, %1, %2" : "=v"(qb0) : "v"(p0), "v"(p1));
    asm("v_cvt_pk_bf16_f32 %0, %1, %2" : "=v"(qb1) : "v"(p2), "v"(p3));
    asm("v_cvt_pk_bf16_f32 %0, %1, %2" : "=v"(qb2) : "v"(p4), "v"(p5));
    asm("v_cvt_pk_bf16_f32 %0, %1, %2" : "=v"(qb3) : "v"(p6), "v"(p7));
    PE(p0, hiB & 1u, d2.x, srcB, MiB)   PE(p1, hiB & 2u, d2.y, srcB, MiB)
    PE(p2, hiB & 4u, d2.z, srcB, MiB)   PE(p3, hiB & 8u, d2.w, srcB, MiB)
    PE(p4, hiB & 16u, d3.x, srcB, MiB)  PE(p5, hiB & 32u, d3.y, srcB, MiB)
    PE(p6, hiB & 64u, d3.z, srcB, MiB)  PE(p7, hiB & 128u, d3.w, srcB, MiB)
    lrB += ((p0 + p1) + (p2 + p3)) + ((p4 + p5) + (p6 + p7));
    unsigned qb4, qb5, qb6, qb7;
    asm("v_cvt_pk_bf16_f32 %0, %1, %2" : "=v"(qb4) : "v"(p0), "v"(p1));
    asm("v_cvt_pk_bf16_f32 %0, %1, %2" : "=v"(qb5) : "v"(p2), "v"(p3));
    asm("v_cvt_pk_bf16_f32 %0, %1, %2" : "=v"(qb6) : "v"(p4), "v"(p5));
    asm("v_cvt_pk_bf16_f32 %0, %1, %2" : "=v"(qb7) : "v"(p6), "v"(p7));
    u32x4 qvB0 = {qb0, qb1, qb2, qb3};
    u32x4 qvB1 = {qb4, qb5, qb6, qb7};
    bf16x8 A0b = __builtin_bit_cast(bf16x8, qvB0);
    bf16x8 A1b = __builtin_bit_cast(bf16x8, qvB1);

    // ---- 16 MFMA: both tiles share B operands ----
    __builtin_amdgcn_s_setprio(1);
    accA[0] = __builtin_amdgcn_mfma_f32_16x16x32_bf16(A0, b0, accA[0], 0, 0, 0);
    accB[0] = __builtin_amdgcn_mfma_f32_16x16x32_bf16(A0b, b0, accB[0], 0, 0, 0);
    accA[1] = __builtin_amdgcn_mfma_f32_16x16x32_bf16(A0, b1, accA[1], 0, 0, 0);
    accB[1] = __builtin_amdgcn_mfma_f32_16x16x32_bf16(A0b, b1, accB[1], 0, 0, 0);
    accA[2] = __builtin_amdgcn_mfma_f32_16x16x32_bf16(A0, b2, accA[2], 0, 0, 0);
    accB[2] = __builtin_amdgcn_mfma_f32_16x16x32_bf16(A0b, b2, accB[2], 0, 0, 0);
    accA[3] = __builtin_amdgcn_mfma_f32_16x16x32_bf16(A0, b3, accA[3], 0, 0, 0);
    accB[3] = __builtin_amdgcn_mfma_f32_16x16x32_bf16(A0b, b3, accB[3], 0, 0, 0);
    accA[0] = __builtin_amdgcn_mfma_f32_16x16x32_bf16(A1, b4, accA[0], 0, 0, 0);
    accB[0] = __builtin_amdgcn_mfma_f32_16x16x32_bf16(A1b, b4, accB[0], 0, 0, 0);
    accA[1] = __builtin_amdgcn_mfma_f32_16x16x32_bf16(A1, b5, accA[1], 0, 0, 0);
    accB[1] = __builtin_amdgcn_mfma_f32_16x16x32_bf16(A1b, b5, accB[1], 0, 0, 0);
    accA[2] = __builtin_amdgcn_mfma_f32_16x16x32_bf16(A1, b6, accA[2], 0, 0, 0);
    accB[2] = __builtin_amdgcn_mfma_f32_16x16x32_bf16(A1b, b6, accB[2], 0, 0, 0);
    accA[3] = __builtin_amdgcn_mfma_f32_16x16x32_bf16(A1, b7, accA[3], 0, 0, 0);
    accB[3] = __builtin_amdgcn_mfma_f32_16x16x32_bf16(A1b, b7, accB[3], 0, 0, 0);
    __builtin_amdgcn_s_setprio(0);
  }
#undef PE

  // row-sums across the 4 g-groups (lanes r, r+16, r+32, r+48)
  lrA += __shfl_xor(lrA, 16);
  lrA += __shfl_xor(lrA, 32);
  lrB += __shfl_xor(lrB, 16);
  lrB += __shfl_xor(lrB, 32);
  if (lane < 16) {
    pl[sp * NROWS + row0p + lane] = lrA;
    pl[sp * NROWS + row0p + 16 + lane] = lrB;
  }
#pragma unroll
  for (int nt = 0; nt < 4; nt++)
#pragma unroll
    for (int q2 = 0; q2 < 4; q2++) {
      pacc[((size_t)sp * NROWS + row0p + 4 * g + q2) * 64 + nt * 16 + r] = accA[nt][q2];
      pacc[((size_t)sp * NROWS + row0p + 16 + 4 * g + q2) * 64 + nt * 16 + r] = accB[nt][q2];
    }
}

// ---------------------------------------------------------------------------
// Kernel C: combine = plain sums (all splits share the same reference Mi).
// ---------------------------------------------------------------------------
__global__ __launch_bounds__(256) void k_comb(
    const float* __restrict__ pl, const float* __restrict__ pacc,
    float* __restrict__ out) {
  int t = blockIdx.x * 256 + threadIdx.x;
  int row = t >> 6, f = t & 63;
  float L = 0.f, o = 0.f;
#pragma unroll
  for (int s2 = 0; s2 < NSPLIT; s2++) {
    L += pl[s2 * NROWS + row];
    o += pacc[((size_t)s2 * NROWS + row) * 64 + f];
  }
  out[t] = o / L;
}

extern "C" void kernel_launch(void* const* d_in, const int* in_sizes, int n_in,
                              void* d_out, int out_size, void* d_ws, size_t ws_size,
                              hipStream_t stream) {
  const float* h = (const float*)d_in[0];
  const float* W = (const float*)d_in[1];
  const float* a = (const float*)d_in[2];
  const int* adj = (const int*)d_in[3];
  float* out = (float*)d_out;

  char* ws = (char*)d_ws;
  unsigned short* WhB = (unsigned short*)ws;           // 1 MB
  float* src = (float*)(ws + 0x100000);                // 32 KB
  float* dst = (float*)(ws + 0x108000);                // 32 KB
  float* dmax = (float*)(ws + 0x110000);               // 256 B
  float* pl = (float*)(ws + 0x110100);                 // 512 KB
  float* pacc = (float*)(ws + 0x190100);               // 32 MB

  hipLaunchKernelGGL(k_prep, dim3(NROWS / 4), dim3(256), 0, stream, h, W, a, WhB, src, dst);
  hipLaunchKernelGGL(k_dmax, dim3(1), dim3(256), 0, stream, dst, dmax);
  hipLaunchKernelGGL(k_attn, dim3(1024), dim3(256), 0, stream,
                     adj, WhB, src, dst, dmax, pl, pacc);
  hipLaunchKernelGGL(k_comb, dim3(NROWS * 64 / 256), dim3(256), 0, stream, pl, pacc, out);
}

// Round 10
// 132.845 us; speedup vs baseline: 1.1833x; 1.1833x over previous
//
#include <hip/hip_runtime.h>

#define NROWS 8192
#define NSPLIT 16
#define JT (NROWS / NSPLIT)  // 512 j's per split
#define NITER (JT / 64)      // 8
#define L2E 1.4426950408889634f

typedef __attribute__((ext_vector_type(4))) float f32x4;
typedef __attribute__((ext_vector_type(8))) __bf16 bf16x8;
typedef __attribute__((ext_vector_type(4))) unsigned int u32x4;

__device__ __forceinline__ unsigned short f2bf(float x) {
  unsigned u = __float_as_uint(x);
  u += 0x7fffu + ((u >> 16) & 1u);
  return (unsigned short)(u >> 16);
}

// ---------------------------------------------------------------------------
// Kernel A: Wh = h@W (stored bf16 in MFMA-B-fragment order), src=Wh@a1, dst=Wh@a2
// src/dst pre-scaled by log2(e) so downstream works in exp2 domain.
// Fragment layout: slot (jc, nt, lane, e) holds Wh[j = 32*jc + 8*(lane>>4) + e][nt*16 + (lane&15)]
// ---------------------------------------------------------------------------
__global__ __launch_bounds__(256) void k_prep(
    const float* __restrict__ h, const float* __restrict__ W,
    const float* __restrict__ a, unsigned short* __restrict__ WhB,
    float* __restrict__ src, float* __restrict__ dst) {
  int i = blockIdx.x * 4 + (threadIdx.x >> 6);  // row
  int lane = threadIdx.x & 63;                  // feature
  const float* hrow = h + (size_t)i * 256;
  float s = 0.f;
#pragma unroll 4
  for (int k = 0; k < 256; k += 4) {
    float4 hv = *(const float4*)(hrow + k);
    s = fmaf(hv.x, W[(k + 0) * 64 + lane], s);
    s = fmaf(hv.y, W[(k + 1) * 64 + lane], s);
    s = fmaf(hv.z, W[(k + 2) * 64 + lane], s);
    s = fmaf(hv.w, W[(k + 3) * 64 + lane], s);
  }
  int nt = lane >> 4, c = lane & 15;
  int gi = (i >> 3) & 3, e = i & 7;
  int idx = ((((i >> 5) * 4 + nt) * 64) + c + 16 * gi) * 8 + e;
  WhB[idx] = f2bf(s);
  float v1 = s * a[lane];
  float v2 = s * a[64 + lane];
#pragma unroll
  for (int d = 32; d; d >>= 1) {
    v1 += __shfl_xor(v1, d);
    v2 += __shfl_xor(v2, d);
  }
  if (lane == 0) {
    src[i] = v1 * L2E;
    dst[i] = v2 * L2E;
  }
}

// ---------------------------------------------------------------------------
// Kernel A2: dmax = max_j dst[j]  (global scalar; 1 block)
// ---------------------------------------------------------------------------
__global__ __launch_bounds__(256) void k_dmax(
    const float* __restrict__ dst, float* __restrict__ dmax) {
  __shared__ float red[4];
  float v = -INFINITY;
  for (int i = threadIdx.x; i < NROWS; i += 256) v = fmaxf(v, dst[i]);
#pragma unroll
  for (int d = 32; d; d >>= 1) v = fmaxf(v, __shfl_xor(v, d));
  if ((threadIdx.x & 63) == 0) red[threadIdx.x >> 6] = v;
  __syncthreads();
  if (threadIdx.x == 0)
    *dmax = fmaxf(fmaxf(red[0], red[1]), fmaxf(red[2], red[3]));
}

// ---------------------------------------------------------------------------
// Kernel B (FUSED, max-TLP): in-wave ballot-pack + masked-softmax + PV.
// One wave = one (16-row tile, split) task; NSPLIT=16 -> 8192 tasks =
// 2048 blocks = 8 blocks/CU = 32 waves/CU (grid was the occupancy cap in
// R2-R9: 1024 blocks = 16 waves/CU). __launch_bounds__(256,8) targets
// <=64 VGPR so all 8 waves/SIMD are resident; body kept lean (single
// chain, rolled loop, no prefetch machinery) to avoid R9's spills.
//
// Phase 1: pack 16 rows x 512 cols via coalesced loads + ballot ->
// mask(rr, ch) held in mk0/mk1 of lane ((ch&3)<<4)+rr (2 u64/lane).
// Phase 2: per 64-col iter, one shfl fetches the row mask; bits gate
// exp2(lrelu(src+dst) - Mi), absolute bound Mi = lrelu(src_i + dmax);
// two 32-col halves, each 4 B-frag loads + 4 MFMA (K=32).
// ---------------------------------------------------------------------------
__global__ __launch_bounds__(256, 8) void k_attn(
    const int* __restrict__ adj, const unsigned short* __restrict__ WhB,
    const float* __restrict__ src, const float* __restrict__ dst,
    const float* __restrict__ dmax,
    float* __restrict__ pl, float* __restrict__ pacc) {
  __shared__ float ldst[JT];
  int task = blockIdx.x * 4 + (threadIdx.x >> 6);  // 0 .. 8191
  int sp = task >> 9;                              // split 0..15 (block-uniform)
  int mt = task & 511;                             // M-tile index
  int lane = threadIdx.x & 63;
  int r = lane & 15;  // row within tile / C col
  int g = lane >> 4;  // k-slot group
  int row0 = mt * 16;
  int jbase = sp * JT;

  // stage this split's dst slice to LDS (block-shared)
  for (int k = threadIdx.x; k < JT; k += 256) ldst[k] = dst[jbase + k];
  __syncthreads();

  // ---- Phase 1: ballot-pack 16 rows x 512 cols into 2 u64 regs/lane ----
  unsigned long long mk0 = 0, mk1 = 0;
  {
    const int* abase = adj + (size_t)row0 * NROWS + jbase + lane;
#pragma unroll
    for (int rr = 0; rr < 16; ++rr) {
      const int* rp = abase + (size_t)rr * NROWS;
#pragma unroll
      for (int ch = 0; ch < 8; ++ch) {
        int v = rp[ch * 64];
        unsigned long long bal = __ballot(v > 0);
        const int holder = ((ch & 3) << 4) + rr;
        if (ch < 4) mk0 = (lane == holder) ? bal : mk0;
        else        mk1 = (lane == holder) ? bal : mk1;
      }
    }
  }

  float srcr = src[row0 + r];
  float vB = srcr + *dmax;
  float Mi = fmaxf(vB, 0.2f * vB);  // upper bound on this row's scores

  float lrow = 0.f;
  f32x4 acc[4] = {f32x4{0.f, 0.f, 0.f, 0.f}, f32x4{0.f, 0.f, 0.f, 0.f},
                  f32x4{0.f, 0.f, 0.f, 0.f}, f32x4{0.f, 0.f, 0.f, 0.f}};
  const bf16x8* Bfr = (const bf16x8*)WhB;

#define PE(P, BIT, DD)                    \
  {                                       \
    float v_ = srcr + (DD);               \
    v_ = fmaxf(v_, 0.2f * v_);            \
    float e_ = exp2f(v_ - Mi);            \
    (P) = (BIT) ? e_ : 0.f;               \
  }
  // one 32-col half: 4 B-frag loads, 8 PE -> pack -> 4 MFMA (K=32)
#define HALF(JC, BITS, DOFF)                                               \
  {                                                                        \
    const bf16x8* bp = Bfr + (size_t)(JC) * 256 + lane;                    \
    bf16x8 b0 = bp[0];                                                     \
    bf16x8 b1 = bp[64];                                                    \
    bf16x8 b2 = bp[128];                                                   \
    bf16x8 b3 = bp[192];                                                   \
    const float4* dlp = (const float4*)(ldst + (DOFF));                    \
    float4 dA = dlp[0];                                                    \
    float4 dB = dlp[1];                                                    \
    unsigned bt_ = (BITS);                                                 \
    float p0, p1, p2, p3, p4, p5, p6, p7;                                  \
    PE(p0, bt_ & 1u, dA.x)   PE(p1, bt_ & 2u, dA.y)                        \
    PE(p2, bt_ & 4u, dA.z)   PE(p3, bt_ & 8u, dA.w)                        \
    PE(p4, bt_ & 16u, dB.x)  PE(p5, bt_ & 32u, dB.y)                       \
    PE(p6, bt_ & 64u, dB.z)  PE(p7, bt_ & 128u, dB.w)                      \
    lrow += ((p0 + p1) + (p2 + p3)) + ((p4 + p5) + (p6 + p7));             \
    unsigned q0, q1, q2, q3;                                               \
    asm("v_cvt_pk_bf16_f32 %0, %1, %2" : "=v"(q0) : "v"(p0), "v"(p1));     \
    asm("v_cvt_pk_bf16_f32 %0, %1, %2" : "=v"(q1) : "v"(p2), "v"(p3));     \
    asm("v_cvt_pk_bf16_f32 %0, %1, %2" : "=v"(q2) : "v"(p4), "v"(p5));     \
    asm("v_cvt_pk_bf16_f32 %0, %1, %2" : "=v"(q3) : "v"(p6), "v"(p7));     \
    u32x4 qv = {q0, q1, q2, q3};                                           \
    bf16x8 Af = __builtin_bit_cast(bf16x8, qv);                            \
    __builtin_amdgcn_s_setprio(1);                                         \
    acc[0] = __builtin_amdgcn_mfma_f32_16x16x32_bf16(Af, b0, acc[0], 0, 0, 0); \
    acc[1] = __builtin_amdgcn_mfma_f32_16x16x32_bf16(Af, b1, acc[1], 0, 0, 0); \
    acc[2] = __builtin_amdgcn_mfma_f32_16x16x32_bf16(Af, b2, acc[2], 0, 0, 0); \
    acc[3] = __builtin_amdgcn_mfma_f32_16x16x32_bf16(Af, b3, acc[3], 0, 0, 0); \
    __builtin_amdgcn_s_setprio(0);                                         \
  }

#pragma unroll 1
  for (int it = 0; it < NITER; ++it) {
    unsigned long long msrc = (it < 4) ? mk0 : mk1;
    unsigned long long pw = __shfl(msrc, ((it & 3) << 4) + r);
    int jc = sp * 16 + 2 * it;
    HALF(jc, (unsigned)(pw >> (8 * g)), it * 64 + 8 * g)
    HALF(jc + 1, (unsigned)(pw >> (32 + 8 * g)), it * 64 + 32 + 8 * g)
  }
#undef HALF
#undef PE

  // row-sum of l across the 4 g-groups (lanes r, r+16, r+32, r+48)
  lrow += __shfl_xor(lrow, 16);
  lrow += __shfl_xor(lrow, 32);
  if (lane < 16) pl[sp * NROWS + row0 + lane] = lrow;
#pragma unroll
  for (int nt = 0; nt < 4; nt++)
#pragma unroll
    for (int q2 = 0; q2 < 4; q2++)
      pacc[((size_t)sp * NROWS + row0 + 4 * g + q2) * 64 + nt * 16 + r] = acc[nt][q2];
}

// ---------------------------------------------------------------------------
// Kernel C: combine = plain sums (all splits share the same reference Mi).
// ---------------------------------------------------------------------------
__global__ __launch_bounds__(256) void k_comb(
    const float* __restrict__ pl, const float* __restrict__ pacc,
    float* __restrict__ out) {
  int t = blockIdx.x * 256 + threadIdx.x;
  int row = t >> 6, f = t & 63;
  float L = 0.f, o = 0.f;
#pragma unroll
  for (int s2 = 0; s2 < NSPLIT; s2++) {
    L += pl[s2 * NROWS + row];
    o += pacc[((size_t)s2 * NROWS + row) * 64 + f];
  }
  out[t] = o / L;
}

extern "C" void kernel_launch(void* const* d_in, const int* in_sizes, int n_in,
                              void* d_out, int out_size, void* d_ws, size_t ws_size,
                              hipStream_t stream) {
  const float* h = (const float*)d_in[0];
  const float* W = (const float*)d_in[1];
  const float* a = (const float*)d_in[2];
  const int* adj = (const int*)d_in[3];
  float* out = (float*)d_out;

  char* ws = (char*)d_ws;
  unsigned short* WhB = (unsigned short*)ws;           // 1 MB
  float* src = (float*)(ws + 0x100000);                // 32 KB
  float* dst = (float*)(ws + 0x108000);                // 32 KB
  float* dmax = (float*)(ws + 0x110000);               // 256 B
  float* pl = (float*)(ws + 0x110100);                 // 512 KB
  float* pacc = (float*)(ws + 0x190100);               // 32 MB

  hipLaunchKernelGGL(k_prep, dim3(NROWS / 4), dim3(256), 0, stream, h, W, a, WhB, src, dst);
  hipLaunchKernelGGL(k_dmax, dim3(1), dim3(256), 0, stream, dst, dmax);
  hipLaunchKernelGGL(k_attn, dim3(2048), dim3(256), 0, stream,
                     adj, WhB, src, dst, dmax, pl, pacc);
  hipLaunchKernelGGL(k_comb, dim3(NROWS * 64 / 256), dim3(256), 0, stream, pl, pacc, out);
}

// Round 13
// 127.384 us; speedup vs baseline: 1.2341x; 1.0429x over previous
//
#include <hip/hip_runtime.h>

#define NROWS 8192
#define NSPLIT 16
#define JT (NROWS / NSPLIT)  // 512 j's per split
#define NITER (JT / 64)      // 8
#define L2E 1.4426950408889634f

typedef __attribute__((ext_vector_type(4))) float f32x4;
typedef __attribute__((ext_vector_type(8))) __bf16 bf16x8;
typedef __attribute__((ext_vector_type(4))) unsigned int u32x4;

__device__ __forceinline__ unsigned short f2bf(float x) {
  unsigned u = __float_as_uint(x);
  u += 0x7fffu + ((u >> 16) & 1u);
  return (unsigned short)(u >> 16);
}

// ---------------------------------------------------------------------------
// Kernel A: Wh = h@W (stored bf16 in MFMA-B-fragment order), src=Wh@a1, dst=Wh@a2
// src/dst pre-scaled by log2(e) so downstream works in exp2 domain.
// Fragment layout: slot (jc, nt, lane, e) holds Wh[j = 32*jc + 8*(lane>>4) + e][nt*16 + (lane&15)]
// ---------------------------------------------------------------------------
__global__ __launch_bounds__(256) void k_prep(
    const float* __restrict__ h, const float* __restrict__ W,
    const float* __restrict__ a, unsigned short* __restrict__ WhB,
    float* __restrict__ src, float* __restrict__ dst) {
  int i = blockIdx.x * 4 + (threadIdx.x >> 6);  // row
  int lane = threadIdx.x & 63;                  // feature
  const float* hrow = h + (size_t)i * 256;
  float s = 0.f;
#pragma unroll 4
  for (int k = 0; k < 256; k += 4) {
    float4 hv = *(const float4*)(hrow + k);
    s = fmaf(hv.x, W[(k + 0) * 64 + lane], s);
    s = fmaf(hv.y, W[(k + 1) * 64 + lane], s);
    s = fmaf(hv.z, W[(k + 2) * 64 + lane], s);
    s = fmaf(hv.w, W[(k + 3) * 64 + lane], s);
  }
  int nt = lane >> 4, c = lane & 15;
  int gi = (i >> 3) & 3, e = i & 7;
  int idx = ((((i >> 5) * 4 + nt) * 64) + c + 16 * gi) * 8 + e;
  WhB[idx] = f2bf(s);
  float v1 = s * a[lane];
  float v2 = s * a[64 + lane];
#pragma unroll
  for (int d = 32; d; d >>= 1) {
    v1 += __shfl_xor(v1, d);
    v2 += __shfl_xor(v2, d);
  }
  if (lane == 0) {
    src[i] = v1 * L2E;
    dst[i] = v2 * L2E;
  }
}

// ---------------------------------------------------------------------------
// Kernel A2: dmax = max_j dst[j]  (global scalar; 1 block)
// ---------------------------------------------------------------------------
__global__ __launch_bounds__(256) void k_dmax(
    const float* __restrict__ dst, float* __restrict__ dmax) {
  __shared__ float red[4];
  float v = -INFINITY;
  for (int i = threadIdx.x; i < NROWS; i += 256) v = fmaxf(v, dst[i]);
#pragma unroll
  for (int d = 32; d; d >>= 1) v = fmaxf(v, __shfl_xor(v, d));
  if ((threadIdx.x & 63) == 0) red[threadIdx.x >> 6] = v;
  __syncthreads();
  if (threadIdx.x == 0)
    *dmax = fmaxf(fmaxf(red[0], red[1]), fmaxf(red[2], red[3]));
}

// ---------------------------------------------------------------------------
// Kernel B (FUSED): in-wave pack of adj + masked-softmax + PV.
// One wave = one (16-row tile, split) task; NSPLIT=16 -> 8192 waves =
// 2048 blocks; __launch_bounds__(256,5) -> <=102 VGPR, 5 blocks/CU =
// 20 waves/CU (R9/R10 lesson: 64-VGPR target spills; 128 caps grid TLP).
//
// Phase 1: int4 loads (1 KB/instr, 4x the bytes per VMEM slot of R7's
// dword loads -> 4x streaming BW at equal pipeline depth) + 4 ballots
// per load + select parking (proven codegen). Scrambled bit semantics:
// word(q,c) bit l <-> col q*256 + 4*l + c; word(rr,q,c) parked in
// mk[q] lane c*16+rr. 32 loads + 128 words per wave.
//
// Phase 2: per 64-col iter: 4 u64 shfls fetch words; shifts give direct
// bit tests; exp2(lrelu(src+dst)-Mi) with absolute bound
// Mi = lrelu(src_i+dmax); two 32-col halves, each 4 B-frags + 4 MFMA.
// pacc stores fully coalesced ([sp][mt][nt][q][lane] layout).
// ---------------------------------------------------------------------------
__global__ __launch_bounds__(256, 5) void k_attn(
    const int* __restrict__ adj, const unsigned short* __restrict__ WhB,
    const float* __restrict__ src, const float* __restrict__ dst,
    const float* __restrict__ dmax,
    float* __restrict__ pl, float* __restrict__ pacc) {
  __shared__ float ldst[JT];
  int task = blockIdx.x * 4 + (threadIdx.x >> 6);  // 0 .. 8191
  int sp = task >> 9;                              // split 0..15 (block-uniform)
  int mt = task & 511;                             // M-tile index
  int lane = threadIdx.x & 63;
  int r = lane & 15;  // row within tile / C col
  int g = lane >> 4;  // k-slot group
  int row0 = mt * 16;
  int jbase = sp * JT;

  // stage this split's dst slice to LDS (block-shared)
  for (int k = threadIdx.x; k < JT; k += 256) ldst[k] = dst[jbase + k];
  __syncthreads();

  // ---- Phase 1: int4 + ballot4 + select parking (16 rows x 512 cols) ----
  unsigned long long mk0 = 0, mk1 = 0;
  {
    const int* abase = adj + (size_t)row0 * NROWS + jbase;
#pragma unroll
    for (int rr = 0; rr < 16; ++rr) {
      const int4* rp = (const int4*)(abase + (size_t)rr * NROWS);
#pragma unroll
      for (int q = 0; q < 2; ++q) {
        int4 v = rp[q * 64 + lane];  // cols q*256 + 4*lane .. +3
        unsigned long long bx = __ballot(v.x > 0);
        unsigned long long by = __ballot(v.y > 0);
        unsigned long long bz = __ballot(v.z > 0);
        unsigned long long bw = __ballot(v.w > 0);
        if (q == 0) {
          mk0 = (lane == 0 + rr) ? bx : mk0;
          mk0 = (lane == 16 + rr) ? by : mk0;
          mk0 = (lane == 32 + rr) ? bz : mk0;
          mk0 = (lane == 48 + rr) ? bw : mk0;
        } else {
          mk1 = (lane == 0 + rr) ? bx : mk1;
          mk1 = (lane == 16 + rr) ? by : mk1;
          mk1 = (lane == 32 + rr) ? bz : mk1;
          mk1 = (lane == 48 + rr) ? bw : mk1;
        }
      }
    }
  }

  float srcr = src[row0 + r];
  float vB = srcr + *dmax;
  float Mi = fmaxf(vB, 0.2f * vB);  // upper bound on this row's scores

  float lrow = 0.f;
  f32x4 acc[4] = {f32x4{0.f, 0.f, 0.f, 0.f}, f32x4{0.f, 0.f, 0.f, 0.f},
                  f32x4{0.f, 0.f, 0.f, 0.f}, f32x4{0.f, 0.f, 0.f, 0.f}};
  const bf16x8* Bfr = (const bf16x8*)WhB;

#define PE(P, BIT, DD)                    \
  {                                       \
    float v_ = srcr + (DD);               \
    v_ = fmaxf(v_, 0.2f * v_);            \
    float e_ = exp2f(v_ - Mi);            \
    (P) = (BIT) ? e_ : 0.f;               \
  }
  // one 32-col half: 4 B-frag loads, 8 PE -> pack -> 4 MFMA (K=32).
  // bits: e=0..3 -> (A_e)&1 ; e=4..7 -> (A_{e-4}>>1)&1  (A_c pre-shifted)
#define HALF(JC, A0_, A1_, A2_, A3_, DOFF)                                 \
  {                                                                        \
    const bf16x8* bp = Bfr + (size_t)(JC) * 256 + lane;                    \
    bf16x8 b0 = bp[0];                                                     \
    bf16x8 b1 = bp[64];                                                    \
    bf16x8 b2 = bp[128];                                                   \
    bf16x8 b3 = bp[192];                                                   \
    const float4* dlp = (const float4*)(ldst + (DOFF));                    \
    float4 dA = dlp[0];                                                    \
    float4 dB = dlp[1];                                                    \
    float p0, p1, p2, p3, p4, p5, p6, p7;                                  \
    PE(p0, (unsigned)(A0_)&1u, dA.x) PE(p1, (unsigned)(A1_)&1u, dA.y)      \
    PE(p2, (unsigned)(A2_)&1u, dA.z) PE(p3, (unsigned)(A3_)&1u, dA.w)      \
    PE(p4, (unsigned)((A0_) >> 1) & 1u, dB.x)                              \
    PE(p5, (unsigned)((A1_) >> 1) & 1u, dB.y)                              \
    PE(p6, (unsigned)((A2_) >> 1) & 1u, dB.z)                              \
    PE(p7, (unsigned)((A3_) >> 1) & 1u, dB.w)                              \
    lrow += ((p0 + p1) + (p2 + p3)) + ((p4 + p5) + (p6 + p7));             \
    unsigned q0, q1, q2, q3;                                               \
    asm("v_cvt_pk_bf16_f32 %0, %1, %2" : "=v"(q0) : "v"(p0), "v"(p1));     \
    asm("v_cvt_pk_bf16_f32 %0, %1, %2" : "=v"(q1) : "v"(p2), "v"(p3));     \
    asm("v_cvt_pk_bf16_f32 %0, %1, %2" : "=v"(q2) : "v"(p4), "v"(p5));     \
    asm("v_cvt_pk_bf16_f32 %0, %1, %2" : "=v"(q3) : "v"(p6), "v"(p7));     \
    u32x4 qv = {q0, q1, q2, q3};                                           \
    bf16x8 Af = __builtin_bit_cast(bf16x8, qv);                            \
    __builtin_amdgcn_s_setprio(1);                                         \
    acc[0] = __builtin_amdgcn_mfma_f32_16x16x32_bf16(Af, b0, acc[0], 0, 0, 0); \
    acc[1] = __builtin_amdgcn_mfma_f32_16x16x32_bf16(Af, b1, acc[1], 0, 0, 0); \
    acc[2] = __builtin_amdgcn_mfma_f32_16x16x32_bf16(Af, b2, acc[2], 0, 0, 0); \
    acc[3] = __builtin_amdgcn_mfma_f32_16x16x32_bf16(Af, b3, acc[3], 0, 0, 0); \
    __builtin_amdgcn_s_setprio(0);                                         \
  }

#pragma unroll 1
  for (int it = 0; it < NITER; ++it) {
    // fetch the 4 words (c=0..3) for this lane's row r, 256-col group it>>2
    unsigned long long ms = (it < 4) ? mk0 : mk1;
    unsigned long long pw0 = __shfl(ms, r);
    unsigned long long pw1 = __shfl(ms, 16 + r);
    unsigned long long pw2 = __shfl(ms, 32 + r);
    unsigned long long pw3 = __shfl(ms, 48 + r);

    int l0 = (it & 3) * 16;
    int s = l0 + 2 * g;  // bit position for (g, e=0) in the lo 32-col half
    unsigned long long a0 = pw0 >> s, a1 = pw1 >> s, a2 = pw2 >> s, a3 = pw3 >> s;
    unsigned long long h0 = a0 >> 8, h1 = a1 >> 8, h2 = a2 >> 8, h3 = a3 >> 8;

    int jc = sp * 16 + 2 * it;
    HALF(jc, a0, a1, a2, a3, it * 64 + 8 * g)
    HALF(jc + 1, h0, h1, h2, h3, it * 64 + 32 + 8 * g)
  }
#undef HALF
#undef PE

  // row-sum of l across the 4 g-groups (lanes r, r+16, r+32, r+48)
  lrow += __shfl_xor(lrow, 16);
  lrow += __shfl_xor(lrow, 32);
  if (lane < 16) pl[sp * NROWS + row0 + lane] = lrow;
  // coalesced pacc: [sp][mt][nt][q][lane], lane = g*16+r
#pragma unroll
  for (int nt = 0; nt < 4; nt++)
#pragma unroll
    for (int q2 = 0; q2 < 4; q2++)
      pacc[((((size_t)sp * 512 + mt) * 4 + nt) * 4 + q2) * 64 + lane] = acc[nt][q2];
}

// ---------------------------------------------------------------------------
// Kernel C: combine = plain sums (all splits share the same reference Mi).
// pacc layout: [sp][mt][nt][q][g*16+r]; row = mt*16 + 4g+q, f = nt*16+r.
// ---------------------------------------------------------------------------
__global__ __launch_bounds__(256) void k_comb(
    const float* __restrict__ pl, const float* __restrict__ pacc,
    float* __restrict__ out) {
  int t = blockIdx.x * 256 + threadIdx.x;
  int row = t >> 6, f = t & 63;
  int mt = row >> 4, rem = row & 15, g = rem >> 2, q = rem & 3;
  int nt = f >> 4, r = f & 15;
  size_t base = ((((size_t)mt) * 4 + nt) * 4 + q) * 64 + g * 16 + r;
  float L = 0.f, o = 0.f;
#pragma unroll
  for (int s2 = 0; s2 < NSPLIT; s2++) {
    L += pl[s2 * NROWS + row];
    o += pacc[(size_t)s2 * (512 * 4 * 4 * 64) + base];
  }
  out[t] = o / L;
}

extern "C" void kernel_launch(void* const* d_in, const int* in_sizes, int n_in,
                              void* d_out, int out_size, void* d_ws, size_t ws_size,
                              hipStream_t stream) {
  const float* h = (const float*)d_in[0];
  const float* W = (const float*)d_in[1];
  const float* a = (const float*)d_in[2];
  const int* adj = (const int*)d_in[3];
  float* out = (float*)d_out;

  char* ws = (char*)d_ws;
  unsigned short* WhB = (unsigned short*)ws;           // 1 MB
  float* src = (float*)(ws + 0x100000);                // 32 KB
  float* dst = (float*)(ws + 0x108000);                // 32 KB
  float* dmax = (float*)(ws + 0x110000);               // 256 B
  float* pl = (float*)(ws + 0x110100);                 // 512 KB
  float* pacc = (float*)(ws + 0x190100);               // 32 MB

  hipLaunchKernelGGL(k_prep, dim3(NROWS / 4), dim3(256), 0, stream, h, W, a, WhB, src, dst);
  hipLaunchKernelGGL(k_dmax, dim3(1), dim3(256), 0, stream, dst, dmax);
  hipLaunchKernelGGL(k_attn, dim3(2048), dim3(256), 0, stream,
                     adj, WhB, src, dst, dmax, pl, pacc);
  hipLaunchKernelGGL(k_comb, dim3(NROWS * 64 / 256), dim3(256), 0, stream, pl, pacc, out);
}